// Round 10
// baseline (334.247 us; speedup 1.0000x reference)
//
#include <hip/hip_runtime.h>
#include <hip/hip_bf16.h>

#define NHEADS 16
#define HDIM 64
#define BATCH 4
#define SEQ 2048
#define CDIM 1024
#define ROWS (BATCH * SEQ)  // 8192
// attention scale 1/sqrt(64) folded with log2(e) so attn uses exp2
#define QSCALE (0.125f * 1.44269504088896f)

typedef __attribute__((ext_vector_type(8))) short short8;
typedef __attribute__((ext_vector_type(4))) float f32x4;
typedef __attribute__((ext_vector_type(4))) unsigned int u32x4;
typedef __attribute__((ext_vector_type(2))) unsigned int u32x2;

__device__ inline short f2bf(float f) {
    unsigned int u = __builtin_bit_cast(unsigned int, f);
    unsigned int r = (u + 0x7fffu + ((u >> 16) & 1u)) >> 16;
    return (short)r;
}

// truncate f32 to bf16 precision (keep high 16 bits) — matches pack_bf2's
// truncation so the in-register denominator equals the bf16 PV numerator sum.
__device__ __forceinline__ float truncbf(float f) {
    return __builtin_bit_cast(float,
        __builtin_bit_cast(unsigned int, f) & 0xffff0000u);
}

__device__ __forceinline__ void gll16(const void* g, void* l) {
    __builtin_amdgcn_global_load_lds(
        (const __attribute__((address_space(1))) unsigned int*)g,
        (__attribute__((address_space(3))) unsigned int*)l, 16, 0, 0);
}

// pack two f32 to bf16x2 (truncate): low = hi16(a), high = hi16(b).
__device__ __forceinline__ unsigned int pack_bf2(float a, float b) {
    return __builtin_amdgcn_perm(__builtin_bit_cast(unsigned int, b),
                                 __builtin_bit_cast(unsigned int, a), 0x07060302u);
}

// ---------------------------------------------------------------------------
// Pre-pass (fused, one dispatch): blocks [0,8192) convert x1/x2 fp32->bf16;
// blocks [8192,8960) transpose+convert wq/wkv -> W^T bf16. Branch is
// block-uniform; LDS T only used by the wtrans role.
// ---------------------------------------------------------------------------
__global__ __launch_bounds__(256) void prep(
    const float* __restrict__ x1, const float* __restrict__ x2,
    short* __restrict__ a1, short* __restrict__ a2, int n8each,
    const float* __restrict__ Wq, short* __restrict__ WQT,
    const float* __restrict__ Wkv, short* __restrict__ WKVT)
{
    __shared__ short T[64][72];
    const int bx = blockIdx.x;
    const int t = threadIdx.x;
    if (bx < 8192) {  // ---- cvt role ----
        int i = bx * 256 + t;
        const float* src = x1;
        short* dst = a1;
        if (i >= n8each) { i -= n8each; src = x2; dst = a2; }
        f32x4 a = ((const f32x4*)src)[i * 2];
        f32x4 b = ((const f32x4*)src)[i * 2 + 1];
        short8 o;
        o[0] = f2bf(a[0]); o[1] = f2bf(a[1]); o[2] = f2bf(a[2]); o[3] = f2bf(a[3]);
        o[4] = f2bf(b[0]); o[5] = f2bf(b[1]); o[6] = f2bf(b[2]); o[7] = f2bf(b[3]);
        ((short8*)dst)[i] = o;
        return;
    }
    // ---- wtrans role: bx2 in [0,768) = (wx in [0,48)) x (ky in [0,16)) ----
    const int bx2 = bx - 8192;
    const int wx = bx2 % 48, ky = bx2 / 48;
    const float* W;
    short* WT;
    int Nw, n0;
    if (wx < 16) { W = Wq;  WT = WQT;  Nw = 1024; n0 = wx * 64; }
    else         { W = Wkv; WT = WKVT; Nw = 2048; n0 = (wx - 16) * 64; }
    const int k0 = ky * 64;
    const int kl = t >> 2, c4 = (t & 3) * 16;
    const float* src = W + (size_t)(k0 + kl) * Nw + n0 + c4;
    short8 s0, s1;
#pragma unroll
    for (int e = 0; e < 2; e++) {
        f32x4 u = *(const f32x4*)(src + e * 4);
        s0[e * 4 + 0] = f2bf(u[0]); s0[e * 4 + 1] = f2bf(u[1]);
        s0[e * 4 + 2] = f2bf(u[2]); s0[e * 4 + 3] = f2bf(u[3]);
        f32x4 v = *(const f32x4*)(src + 8 + e * 4);
        s1[e * 4 + 0] = f2bf(v[0]); s1[e * 4 + 1] = f2bf(v[1]);
        s1[e * 4 + 2] = f2bf(v[2]); s1[e * 4 + 3] = f2bf(v[3]);
    }
    *(short8*)&T[kl][c4] = s0;
    *(short8*)&T[kl][c4 + 8] = s1;
    __syncthreads();
#pragma unroll
    for (int pass = 0; pass < 2; pass++) {
        int n = (t >> 3) + pass * 32;
        short8 o;
#pragma unroll
        for (int e = 0; e < 8; e++) o[e] = T[(t & 7) * 8 + e][n];
        *(short8*)(WT + (size_t)(n0 + n) * 1024 + k0 + (t & 7) * 8) = o;
    }
}

// ---------------------------------------------------------------------------
// Fused GEMM with RANGE-PARTITIONED swizzle (r9, measured <140us): lin<512 is
// the Q-GEMM with r1's Q swizzle; lin>=512 is the KV-GEMM with r1's KV
// swizzle (512%8==0 keeps per-part XCD assignment identical to the split
// dispatches: per-XCD working set 2.25/4.25 MB). K-loop = m97 128x128/BK=32.
// ---------------------------------------------------------------------------
__global__ __launch_bounds__(256) void gemm_all(
    const short* __restrict__ A1,    // [8192][1024] bf16 (x1)
    const short* __restrict__ A2,    // [8192][1024] bf16 (x2)
    const short* __restrict__ WQT,   // [1024][1024] bf16
    const short* __restrict__ WKVT,  // [2048][1024] bf16
    const float* __restrict__ bq,    // [1024]
    const float* __restrict__ bkv,   // [2048]
    const float* __restrict__ gq, const float* __restrict__ btq,
    const float* __restrict__ gk, const float* __restrict__ btk,
    short* __restrict__ QOut,        // [B][H][N][64] bf16 (pre-scaled QSCALE)
    short* __restrict__ KOut,        // [B][H][N][64] bf16
    short* __restrict__ VT)          // [B][H][64][N] bf16
{
    __shared__ __align__(16) char smem[34816];
    short (*As)[32] = (short (*)[32])smem;           // [128][32]
    short (*Bs)[32] = (short (*)[32])(smem + 8192);  // [128][32]

    const int tid = threadIdx.x;
    const int wave = tid >> 6, lane = tid & 63;
    const int wr = wave >> 1, wc = wave & 1;
    const int quad = lane >> 4, l15 = lane & 15;

    const int lin = blockIdx.x;                      // grid (1536)
    const bool isQ = lin < 512;
    int rblk, cblk;
    if (isQ) {
        const int swz = (lin & 7) * 64 + (lin >> 3);       // r1 Q swizzle
        rblk = swz >> 3; cblk = swz & 7;
    } else {
        const int kl = lin - 512;                          // kl%8 == lin%8
        const int swz = (kl & 7) * 128 + (kl >> 3);        // r1 KV swizzle
        rblk = swz >> 4; cblk = swz & 15;
    }
    const short* Ap = isQ ? A1 : A2;
    const short* BT = isQ ? WQT : WKVT;

    f32x4 acc[4][4];
#pragma unroll
    for (int i = 0; i < 4; i++)
#pragma unroll
        for (int j = 0; j < 4; j++) acc[i][j] = f32x4{0.f, 0.f, 0.f, 0.f};

    const int srow = wave * 32 + (lane >> 2);
    const int scol = (lane & 3) * 8;

    for (int k0 = 0; k0 < CDIM; k0 += 32) {
        __syncthreads();
#pragma unroll
        for (int c = 0; c < 2; c++) {
            gll16(Ap + (size_t)(rblk * 128 + srow + c * 16) * CDIM + k0 + scol,
                  &As[srow + c * 16][scol]);
            gll16(BT + (size_t)(cblk * 128 + srow + c * 16) * CDIM + k0 + scol,
                  &Bs[srow + c * 16][scol]);
        }
        __syncthreads();

        short8 af[4], bfr[4];
#pragma unroll
        for (int i = 0; i < 4; i++)
            af[i] = *(const short8*)&As[wr * 64 + i * 16 + l15][quad * 8];
#pragma unroll
        for (int j = 0; j < 4; j++)
            bfr[j] = *(const short8*)&Bs[wc * 64 + j * 16 + l15][quad * 8];
#pragma unroll
        for (int i = 0; i < 4; i++)
#pragma unroll
            for (int j = 0; j < 4; j++)
                acc[i][j] = __builtin_amdgcn_mfma_f32_16x16x32_bf16(af[i], bfr[j], acc[i][j], 0, 0, 0);
    }

    const int col0 = cblk * 128 + wc * 64;
    const int g = col0 >> 6;   // Q: [0,16); KV: [0,32)

    if (isQ || g < NHEADS) {  // ---- Q or K: bias + per-head LayerNorm ----
        const float* bias  = isQ ? bq : bkv;
        const float* gamma = isQ ? gq : gk;
        const float* beta  = isQ ? btq : btk;
        short* Out = isQ ? QOut : KOut;
        const float scale = isQ ? QSCALE : 1.f;
        const int h = g;
        float bv[4], gv[4], btv[4];
#pragma unroll
        for (int j = 0; j < 4; j++) {
            int d = j * 16 + l15;
            bv[j] = bias[col0 + d];
            gv[j] = gamma[d];
            btv[j] = beta[d];
        }
#pragma unroll
        for (int i = 0; i < 4; i++) {
            int rowl = rblk * 128 + wr * 64 + i * 16 + quad * 4;
#pragma unroll
            for (int reg = 0; reg < 4; reg++) {
                float x[4], s = 0.f, s2 = 0.f;
#pragma unroll
                for (int j = 0; j < 4; j++) {
                    x[j] = acc[i][j][reg] + bv[j];
                    s += x[j];
                    s2 += x[j] * x[j];
                }
#pragma unroll
                for (int m = 1; m < 16; m <<= 1) {
                    s += __shfl_xor(s, m);
                    s2 += __shfl_xor(s2, m);
                }
                float mean = s * (1.f / 64.f);
                float var = s2 * (1.f / 64.f) - mean * mean;
                float rstd = rsqrtf(var + 1e-5f);
                int r = rowl + reg;
                int b = r >> 11, n = r & (SEQ - 1);
                size_t base = (((size_t)b * NHEADS + h) * SEQ + n) * 64;
#pragma unroll
                for (int j = 0; j < 4; j++) {
                    float y = ((x[j] - mean) * rstd * gv[j] + btv[j]) * scale;
                    Out[base + j * 16 + l15] = f2bf(y);
                }
            }
        }
    } else {  // ---- V: bias -> wave-local transpose (Ts aliases As/Bs) ----
        const int h = g - NHEADS;
        __syncthreads();  // As/Bs dead for ALL waves before Ts alias
        short (*Ts)[64][68] = (short (*)[64][68])smem;  // [4][64][68]
#pragma unroll
        for (int i = 0; i < 4; i++)
#pragma unroll
            for (int reg = 0; reg < 4; reg++)
#pragma unroll
                for (int j = 0; j < 4; j++)
                    Ts[wave][i * 16 + quad * 4 + reg][j * 16 + l15] =
                        f2bf(acc[i][j][reg] + bkv[col0 + j * 16 + l15]);
        const int r = rblk * 128 + wr * 64 + lane;
        const int b = r >> 11, n = r & (SEQ - 1);
        const size_t vtbase = (((size_t)b * NHEADS + h) * 64) * SEQ;
#pragma unroll
        for (int e8 = 0; e8 < 8; e8++) {
            short8 v = *(const short8*)&Ts[wave][lane][e8 * 8];
#pragma unroll
            for (int e = 0; e < 8; e++)
                VT[vtbase + (size_t)(e8 * 8 + e) * SEQ + n] = v[e];
        }
    }
}

// Band store with COMPILE-TIME jd index: keeps o[][] in registers (dynamic
// indexing demotes the whole array to scratch).
template <int JD, bool FIRST>
__device__ __forceinline__ void band_store(float* __restrict__ Ot,
                                           const f32x4 (&o)[4][4],
                                           int l15, int q) {
#pragma unroll
    for (int qc = 0; qc < 4; qc++)
#pragma unroll
        for (int reg = 0; reg < 4; reg++) {
            float* dst = &Ot[(qc * 16 + l15) * 68 + JD * 16 + q * 4 + reg];
            if (FIRST) *dst = o[JD][qc][reg];
            else       *dst += o[JD][qc][reg];
        }
}

// One rotated pipeline body (tile t) — r7 v9b structure, with the ones-MFMA
// denominator replaced by an in-register truncation-matched row-sum (v11):
// lane (quad,l15) holds z[reg] = S^T[key=kt*16+quad*4+reg][qrow=qc*16+l15];
// summing truncbf(exp2(z)) over reg,kt (here) and quad (shfl, epilogue)
// equals the old ones-MFMA sum of bf16 P values (f32 accum, reorder ~1ulp).
// Removes 4 of 20 MFMAs per tile-step. INVARIANTS: kfCur=K(t), vfPN=V(t-1),
// PdR=P(t-1).
__device__ __forceinline__ void attn_body(
    int t, bool doLoad,
    const short* __restrict__ kbase, const short* __restrict__ vbase,
    const short8 (&qf)[4][2],
    short8 (&kfCur)[2][2], short8 (&kfNxt)[2][2], short8 (&vfPN)[4],
    unsigned int* __restrict__ PdW, unsigned int* __restrict__ PdR,
    int l15, int q, f32x4 (&o)[4][4], float (&rden)[4])
{
    short8 pf[4];
#pragma unroll
    for (int qc = 0; qc < 4; qc++) {
        u32x4 pr = *(const u32x4*)&PdR[(qc * 16 + l15) * 20 + 4 * q];
        pf[qc] = __builtin_bit_cast(short8, pr);
    }

#pragma unroll
    for (int kt = 0; kt < 2; kt++)
#pragma unroll
        for (int qc = 0; qc < 4; qc++) {
            f32x4 z = f32x4{0.f, 0.f, 0.f, 0.f};
            z = __builtin_amdgcn_mfma_f32_16x16x32_bf16(kfCur[kt][0], qf[qc][0], z, 0, 0, 0);
            z = __builtin_amdgcn_mfma_f32_16x16x32_bf16(kfCur[kt][1], qf[qc][1], z, 0, 0, 0);
            float e0 = __builtin_amdgcn_exp2f(z[0]);
            float e1 = __builtin_amdgcn_exp2f(z[1]);
            float e2 = __builtin_amdgcn_exp2f(z[2]);
            float e3 = __builtin_amdgcn_exp2f(z[3]);
            u32x2 d2;
            d2[0] = pack_bf2(e0, e1);
            d2[1] = pack_bf2(e2, e3);
            *(u32x2*)&PdW[(qc * 16 + l15) * 20 + kt * 8 + 2 * q] = d2;
            rden[qc] += (truncbf(e0) + truncbf(e1)) + (truncbf(e2) + truncbf(e3));
        }

    if (doLoad) {
#pragma unroll
        for (int kt = 0; kt < 2; kt++)
#pragma unroll
            for (int dh = 0; dh < 2; dh++)
                kfNxt[kt][dh] = *(const short8*)(kbase +
                    (size_t)((t + 1) * 128 + kt * 16) * 64 + dh * 32);
    }

#pragma unroll
    for (int jd = 0; jd < 4; jd++)
#pragma unroll
        for (int qc = 0; qc < 4; qc++)
            o[jd][qc] = __builtin_amdgcn_mfma_f32_16x16x32_bf16(vfPN[jd], pf[qc], o[jd][qc], 0, 0, 0);

    if (doLoad) {
#pragma unroll
        for (int jd = 0; jd < 4; jd++)
            vfPN[jd] = *(const short8*)(vbase + (size_t)(jd * 16) * SEQ + (t + 1) * 128);
    }
}

// ---------------------------------------------------------------------------
// Flash attention v11: r7 v9b pipeline (best measured 140.4-141.4us) with
// the denominator ones-MFMA removed (-20% MFMA work, -16 VGPR). r8 lesson
// kept: 2 blocks/CU fat waves is the optimum — __launch_bounds__(256,2).
// bh-chunked XCD swizzle kept (FETCH -63% proven).
// ---------------------------------------------------------------------------
__global__ __launch_bounds__(256, 2) void attn_fa(
    const short* __restrict__ Q,   // [B][H][N][64] bf16, pre-scaled QSCALE
    const short* __restrict__ Kk,  // [B][H][N][64] bf16
    const short* __restrict__ VT,  // [B][H][64][N] bf16
    float* __restrict__ Out)       // [B][N][1024] fp32
{
    __shared__ __align__(16) char smem_raw[40960];

    const int tid = threadIdx.x;
    const int w = tid >> 6, lane = tid & 63;
    const int q = lane >> 4, l15 = lane & 15;
    // bh-chunked XCD swizzle: XCD k gets bh in [8k,8k+8), qt fastest.
    const int lin = blockIdx.y * 64 + blockIdx.x;
    const int swz = (lin & 7) * 256 + (lin >> 3);
    const int bh = swz >> 5;
    const int qt = swz & 31;
    const int b = bh >> 4, h = bh & 15;
    const size_t hb = (size_t)bh * SEQ * 64;
    const size_t vb = (size_t)bh * 64 * SEQ;

    unsigned int* PdA = (unsigned int*)smem_raw + w * 2560;  // even-t buffer
    unsigned int* PdB = PdA + 1280;                          // odd-t buffer
    float* Ot = (float*)smem_raw;                            // [64][68]
    float* Lred = (float*)smem_raw + 64 * 68;                // [4][64]

    short8 qf[4][2];
#pragma unroll
    for (int qc = 0; qc < 4; qc++)
#pragma unroll
        for (int dh = 0; dh < 2; dh++)
            qf[qc][dh] = *(const short8*)(Q + hb +
                (size_t)(qt * 64 + qc * 16 + l15) * 64 + dh * 32 + q * 8);

    f32x4 o[4][4];
#pragma unroll
    for (int jd = 0; jd < 4; jd++)
#pragma unroll
        for (int qc = 0; qc < 4; qc++) o[jd][qc] = f32x4{0.f, 0.f, 0.f, 0.f};
    float rden[4] = {0.f, 0.f, 0.f, 0.f};

    const short* kbase = Kk + hb + (size_t)(w * 32 + l15) * 64 + q * 8;
    const short* vbase = VT + vb + (size_t)l15 * SEQ + w * 32 + q * 8;

    short8 kfA[2][2], kfB[2][2], vfA[4], vfB[4];

    // ---- prologue: load K/V(0), QK(0)->PdA (+rden), load K(1) AND V(1) ----
#pragma unroll
    for (int kt = 0; kt < 2; kt++)
#pragma unroll
        for (int dh = 0; dh < 2; dh++)
            kfA[kt][dh] = *(const short8*)(kbase + (size_t)(kt * 16) * 64 + dh * 32);
#pragma unroll
    for (int jd = 0; jd < 4; jd++)
        vfA[jd] = *(const short8*)(vbase + (size_t)(jd * 16) * SEQ);
#pragma unroll
    for (int kt = 0; kt < 2; kt++)
#pragma unroll
        for (int qc = 0; qc < 4; qc++) {
            f32x4 z = f32x4{0.f, 0.f, 0.f, 0.f};
            z = __builtin_amdgcn_mfma_f32_16x16x32_bf16(kfA[kt][0], qf[qc][0], z, 0, 0, 0);
            z = __builtin_amdgcn_mfma_f32_16x16x32_bf16(kfA[kt][1], qf[qc][1], z, 0, 0, 0);
            float e0 = __builtin_amdgcn_exp2f(z[0]);
            float e1 = __builtin_amdgcn_exp2f(z[1]);
            float e2 = __builtin_amdgcn_exp2f(z[2]);
            float e3 = __builtin_amdgcn_exp2f(z[3]);
            u32x2 d2;
            d2[0] = pack_bf2(e0, e1);
            d2[1] = pack_bf2(e2, e3);
            *(u32x2*)&PdA[(qc * 16 + l15) * 20 + kt * 8 + 2 * q] = d2;
            rden[qc] += (truncbf(e0) + truncbf(e1)) + (truncbf(e2) + truncbf(e3));
        }
#pragma unroll
    for (int kt = 0; kt < 2; kt++)
#pragma unroll
        for (int dh = 0; dh < 2; dh++)
            kfB[kt][dh] = *(const short8*)(kbase + (size_t)(128 + kt * 16) * 64 + dh * 32);
#pragma unroll
    for (int jd = 0; jd < 4; jd++)
        vfB[jd] = *(const short8*)(vbase + (size_t)(jd * 16) * SEQ + 128);

    for (int t = 1; t < 15; t += 2) {
        attn_body(t,     true, kbase, vbase, qf, kfB, kfA, vfA, PdB, PdA, l15, q, o, rden);
        attn_body(t + 1, true, kbase, vbase, qf, kfA, kfB, vfB, PdA, PdB, l15, q, o, rden);
    }
    attn_body(15, false, kbase, vbase, qf, kfB, kfA, vfA, PdB, PdA, l15, q, o, rden);

    // ---- drain: PV(15) from PdB with vfB (= V(15), loaded by body(14)) ----
    {
        short8 pf[4];
#pragma unroll
        for (int qc = 0; qc < 4; qc++) {
            u32x4 pr = *(const u32x4*)&PdB[(qc * 16 + l15) * 20 + 4 * q];
            pf[qc] = __builtin_bit_cast(short8, pr);
        }
#pragma unroll
        for (int jd = 0; jd < 4; jd++)
#pragma unroll
            for (int qc = 0; qc < 4; qc++)
                o[jd][qc] = __builtin_amdgcn_mfma_f32_16x16x32_bf16(vfB[jd], pf[qc], o[jd][qc], 0, 0, 0);
    }

    // denominator: reduce the per-lane partial (8 keys/tile) across the
    // quad lanes (lane bits 4,5) -> every lane holds the 512-key wave sum.
#pragma unroll
    for (int qc = 0; qc < 4; qc++) {
        rden[qc] += __shfl_xor(rden[qc], 16);
        rden[qc] += __shfl_xor(rden[qc], 32);
    }

    // ---- epilogue: phase-accumulate O^T into Ot (aliases Pd), then store ----
    __syncthreads();  // Pd dead everywhere
#pragma unroll
    for (int p = 0; p < 4; p++) {
        const int jd = (w + p) & 3;
        if (p == 0) {
            switch (jd) {
            case 0: band_store<0, true>(Ot, o, l15, q); break;
            case 1: band_store<1, true>(Ot, o, l15, q); break;
            case 2: band_store<2, true>(Ot, o, l15, q); break;
            case 3: band_store<3, true>(Ot, o, l15, q); break;
            }
            if (q == 0) {
#pragma unroll
                for (int qc = 0; qc < 4; qc++)
                    Lred[w * 64 + qc * 16 + l15] = rden[qc];
            }
        } else {
            switch (jd) {
            case 0: band_store<0, false>(Ot, o, l15, q); break;
            case 1: band_store<1, false>(Ot, o, l15, q); break;
            case 2: band_store<2, false>(Ot, o, l15, q); break;
            case 3: band_store<3, false>(Ot, o, l15, q); break;
            }
        }
        __syncthreads();
    }

    // coalesced store: 4 lanes cover one row's 16 floats each -> 64 B lines
    const int row = tid >> 2, c = tid & 3;
    float l = Lred[row] + Lred[64 + row] + Lred[128 + row] + Lred[192 + row];
    float inv = 1.f / l;
    float* obase = Out + ((size_t)b * SEQ + qt * 64 + row) * CDIM + h * 64;
#pragma unroll
    for (int i = 0; i < 4; i++) {
        f32x4 t = *(const f32x4*)&Ot[row * 68 + (c + 4 * i) * 4];
        *(f32x4*)(obase + (c + 4 * i) * 4) = t * inv;
    }
}

extern "C" void kernel_launch(void* const* d_in, const int* in_sizes, int n_in,
                              void* d_out, int out_size, void* d_ws, size_t ws_size,
                              hipStream_t stream) {
    const float* x1 = (const float*)d_in[0];
    const float* x2 = (const float*)d_in[1];
    const float* wq = (const float*)d_in[2];
    const float* bq = (const float*)d_in[3];
    const float* wkv = (const float*)d_in[4];
    const float* bkv = (const float*)d_in[5];
    const float* gq = (const float*)d_in[6];
    const float* btq = (const float*)d_in[7];
    const float* gk = (const float*)d_in[8];
    const float* btk = (const float*)d_in[9];
    float* out = (float*)d_out;

    short* a1 = (short*)d_ws;                          // [8192][1024] bf16
    short* a2 = a1 + (size_t)ROWS * CDIM;
    short* wqT = a2 + (size_t)ROWS * CDIM;             // [1024][1024]
    short* wkvT = wqT + (size_t)CDIM * CDIM;           // [2048][1024]
    short* qln = wkvT + (size_t)2 * CDIM * CDIM;       // [B][H][N][64]
    short* kln = qln + (size_t)ROWS * CDIM;            // [B][H][N][64]
    short* vt = kln + (size_t)ROWS * CDIM;             // [B][H][64][N]

    const int n8 = ROWS * CDIM / 8;
    prep<<<dim3(8192 + 768), 256, 0, stream>>>(x1, x2, a1, a2, n8,
                                               wq, wqT, wkv, wkvT);
    gemm_all<<<dim3(1536), 256, 0, stream>>>(a1, a2, wqT, wkvT, bq, bkv,
                                             gq, btq, gk, btk, qln, kln, vt);
    attn_fa<<<dim3(64, 32), 256, 0, stream>>>(qln, kln, vt, out);
}

// Round 11
// 330.437 us; speedup vs baseline: 1.0115x; 1.0115x over previous
//
#include <hip/hip_runtime.h>
#include <hip/hip_bf16.h>

#define NHEADS 16
#define HDIM 64
#define BATCH 4
#define SEQ 2048
#define CDIM 1024
#define ROWS (BATCH * SEQ)  // 8192
// attention scale 1/sqrt(64) folded with log2(e) so attn uses exp2
#define QSCALE (0.125f * 1.44269504088896f)

typedef __attribute__((ext_vector_type(8))) short short8;
typedef __attribute__((ext_vector_type(4))) float f32x4;
typedef __attribute__((ext_vector_type(4))) unsigned int u32x4;
typedef __attribute__((ext_vector_type(2))) unsigned int u32x2;

__device__ inline short f2bf(float f) {
    unsigned int u = __builtin_bit_cast(unsigned int, f);
    unsigned int r = (u + 0x7fffu + ((u >> 16) & 1u)) >> 16;
    return (short)r;
}

__device__ __forceinline__ void gll16(const void* g, void* l) {
    __builtin_amdgcn_global_load_lds(
        (const __attribute__((address_space(1))) unsigned int*)g,
        (__attribute__((address_space(3))) unsigned int*)l, 16, 0, 0);
}

// pack two f32 to bf16x2 (truncate): low = hi16(a), high = hi16(b).
// truncation bias cancels between PV numerator and ones-MFMA denominator.
__device__ __forceinline__ unsigned int pack_bf2(float a, float b) {
    return __builtin_amdgcn_perm(__builtin_bit_cast(unsigned int, b),
                                 __builtin_bit_cast(unsigned int, a), 0x07060302u);
}

// ---------------------------------------------------------------------------
// Pre-pass 1 (fused): fp32 -> bf16 for x1 AND x2 in one dispatch.
// (r10's prep mega-fusion with wtrans was +2us — reverted to r9's pair.)
// ---------------------------------------------------------------------------
__global__ __launch_bounds__(256) void cvt2_bf16(const float* __restrict__ s1,
                                                 const float* __restrict__ s2,
                                                 short* __restrict__ d1,
                                                 short* __restrict__ d2, int n8each) {
    int i = blockIdx.x * 256 + threadIdx.x;
    const float* src = s1;
    short* dst = d1;
    if (i >= n8each) { i -= n8each; src = s2; dst = d2; }
    f32x4 a = ((const f32x4*)src)[i * 2];
    f32x4 b = ((const f32x4*)src)[i * 2 + 1];
    short8 o;
    o[0] = f2bf(a[0]); o[1] = f2bf(a[1]); o[2] = f2bf(a[2]); o[3] = f2bf(a[3]);
    o[4] = f2bf(b[0]); o[5] = f2bf(b[1]); o[6] = f2bf(b[2]); o[7] = f2bf(b[3]);
    ((short8*)dst)[i] = o;
}

// ---------------------------------------------------------------------------
// Pre-pass 2 (fused): W [K=1024][Nw] fp32 -> W^T [Nw][1024] bf16, wq AND wkv.
// blockIdx.x < 16 -> wq (Nw=1024); else wkv (Nw=2048).
// ---------------------------------------------------------------------------
__global__ __launch_bounds__(256) void wtrans2(const float* __restrict__ Wq,
                                               short* __restrict__ WQT,
                                               const float* __restrict__ Wkv,
                                               short* __restrict__ WKVT) {
    __shared__ short T[64][72];
    const int t = threadIdx.x;
    const int bx = blockIdx.x;
    const float* W;
    short* WT;
    int Nw, n0;
    if (bx < 16) { W = Wq;  WT = WQT;  Nw = 1024; n0 = bx * 64; }
    else         { W = Wkv; WT = WKVT; Nw = 2048; n0 = (bx - 16) * 64; }
    const int k0 = blockIdx.y * 64;
    const int kl = t >> 2, c4 = (t & 3) * 16;
    const float* src = W + (size_t)(k0 + kl) * Nw + n0 + c4;
    short8 s0, s1;
#pragma unroll
    for (int e = 0; e < 2; e++) {
        f32x4 u = *(const f32x4*)(src + e * 4);
        s0[e * 4 + 0] = f2bf(u[0]); s0[e * 4 + 1] = f2bf(u[1]);
        s0[e * 4 + 2] = f2bf(u[2]); s0[e * 4 + 3] = f2bf(u[3]);
        f32x4 v = *(const f32x4*)(src + 8 + e * 4);
        s1[e * 4 + 0] = f2bf(v[0]); s1[e * 4 + 1] = f2bf(v[1]);
        s1[e * 4 + 2] = f2bf(v[2]); s1[e * 4 + 3] = f2bf(v[3]);
    }
    *(short8*)&T[kl][c4] = s0;
    *(short8*)&T[kl][c4 + 8] = s1;
    __syncthreads();
#pragma unroll
    for (int pass = 0; pass < 2; pass++) {
        int n = (t >> 3) + pass * 32;
        short8 o;
#pragma unroll
        for (int e = 0; e < 8; e++) o[e] = T[(t & 7) * 8 + e][n];
        *(short8*)(WT + (size_t)(n0 + n) * 1024 + k0 + (t & 7) * 8) = o;
    }
}

// ---------------------------------------------------------------------------
// Fused GEMM with RANGE-PARTITIONED swizzle (r9, measured <140us): lin<512 is
// the Q-GEMM with r1's Q swizzle; lin>=512 is the KV-GEMM with r1's KV
// swizzle (512%8==0 keeps per-part XCD assignment identical to the split
// dispatches: per-XCD working set 2.25/4.25 MB). K-loop = m97 128x128/BK=32.
// ---------------------------------------------------------------------------
__global__ __launch_bounds__(256) void gemm_all(
    const short* __restrict__ A1,    // [8192][1024] bf16 (x1)
    const short* __restrict__ A2,    // [8192][1024] bf16 (x2)
    const short* __restrict__ WQT,   // [1024][1024] bf16
    const short* __restrict__ WKVT,  // [2048][1024] bf16
    const float* __restrict__ bq,    // [1024]
    const float* __restrict__ bkv,   // [2048]
    const float* __restrict__ gq, const float* __restrict__ btq,
    const float* __restrict__ gk, const float* __restrict__ btk,
    short* __restrict__ QOut,        // [B][H][N][64] bf16 (pre-scaled QSCALE)
    short* __restrict__ KOut,        // [B][H][N][64] bf16
    short* __restrict__ VT)          // [B][H][64][N] bf16
{
    __shared__ __align__(16) char smem[34816];
    short (*As)[32] = (short (*)[32])smem;           // [128][32]
    short (*Bs)[32] = (short (*)[32])(smem + 8192);  // [128][32]

    const int tid = threadIdx.x;
    const int wave = tid >> 6, lane = tid & 63;
    const int wr = wave >> 1, wc = wave & 1;
    const int quad = lane >> 4, l15 = lane & 15;

    const int lin = blockIdx.x;                      // grid (1536)
    const bool isQ = lin < 512;
    int rblk, cblk;
    if (isQ) {
        const int swz = (lin & 7) * 64 + (lin >> 3);       // r1 Q swizzle
        rblk = swz >> 3; cblk = swz & 7;
    } else {
        const int kl = lin - 512;                          // kl%8 == lin%8
        const int swz = (kl & 7) * 128 + (kl >> 3);        // r1 KV swizzle
        rblk = swz >> 4; cblk = swz & 15;
    }
    const short* Ap = isQ ? A1 : A2;
    const short* BT = isQ ? WQT : WKVT;

    f32x4 acc[4][4];
#pragma unroll
    for (int i = 0; i < 4; i++)
#pragma unroll
        for (int j = 0; j < 4; j++) acc[i][j] = f32x4{0.f, 0.f, 0.f, 0.f};

    const int srow = wave * 32 + (lane >> 2);
    const int scol = (lane & 3) * 8;

    for (int k0 = 0; k0 < CDIM; k0 += 32) {
        __syncthreads();
#pragma unroll
        for (int c = 0; c < 2; c++) {
            gll16(Ap + (size_t)(rblk * 128 + srow + c * 16) * CDIM + k0 + scol,
                  &As[srow + c * 16][scol]);
            gll16(BT + (size_t)(cblk * 128 + srow + c * 16) * CDIM + k0 + scol,
                  &Bs[srow + c * 16][scol]);
        }
        __syncthreads();

        short8 af[4], bfr[4];
#pragma unroll
        for (int i = 0; i < 4; i++)
            af[i] = *(const short8*)&As[wr * 64 + i * 16 + l15][quad * 8];
#pragma unroll
        for (int j = 0; j < 4; j++)
            bfr[j] = *(const short8*)&Bs[wc * 64 + j * 16 + l15][quad * 8];
#pragma unroll
        for (int i = 0; i < 4; i++)
#pragma unroll
            for (int j = 0; j < 4; j++)
                acc[i][j] = __builtin_amdgcn_mfma_f32_16x16x32_bf16(af[i], bfr[j], acc[i][j], 0, 0, 0);
    }

    const int col0 = cblk * 128 + wc * 64;
    const int g = col0 >> 6;   // Q: [0,16); KV: [0,32)

    if (isQ || g < NHEADS) {  // ---- Q or K: bias + per-head LayerNorm ----
        const float* bias  = isQ ? bq : bkv;
        const float* gamma = isQ ? gq : gk;
        const float* beta  = isQ ? btq : btk;
        short* Out = isQ ? QOut : KOut;
        const float scale = isQ ? QSCALE : 1.f;
        const int h = g;
        float bv[4], gv[4], btv[4];
#pragma unroll
        for (int j = 0; j < 4; j++) {
            int d = j * 16 + l15;
            bv[j] = bias[col0 + d];
            gv[j] = gamma[d];
            btv[j] = beta[d];
        }
#pragma unroll
        for (int i = 0; i < 4; i++) {
            int rowl = rblk * 128 + wr * 64 + i * 16 + quad * 4;
#pragma unroll
            for (int reg = 0; reg < 4; reg++) {
                float x[4], s = 0.f, s2 = 0.f;
#pragma unroll
                for (int j = 0; j < 4; j++) {
                    x[j] = acc[i][j][reg] + bv[j];
                    s += x[j];
                    s2 += x[j] * x[j];
                }
#pragma unroll
                for (int m = 1; m < 16; m <<= 1) {
                    s += __shfl_xor(s, m);
                    s2 += __shfl_xor(s2, m);
                }
                float mean = s * (1.f / 64.f);
                float var = s2 * (1.f / 64.f) - mean * mean;
                float rstd = rsqrtf(var + 1e-5f);
                int r = rowl + reg;
                int b = r >> 11, n = r & (SEQ - 1);
                size_t base = (((size_t)b * NHEADS + h) * SEQ + n) * 64;
#pragma unroll
                for (int j = 0; j < 4; j++) {
                    float y = ((x[j] - mean) * rstd * gv[j] + btv[j]) * scale;
                    Out[base + j * 16 + l15] = f2bf(y);
                }
            }
        }
    } else {  // ---- V: bias -> wave-local transpose (Ts aliases As/Bs) ----
        const int h = g - NHEADS;
        __syncthreads();  // As/Bs dead for ALL waves before Ts alias
        short (*Ts)[64][68] = (short (*)[64][68])smem;  // [4][64][68]
#pragma unroll
        for (int i = 0; i < 4; i++)
#pragma unroll
            for (int reg = 0; reg < 4; reg++)
#pragma unroll
                for (int j = 0; j < 4; j++)
                    Ts[wave][i * 16 + quad * 4 + reg][j * 16 + l15] =
                        f2bf(acc[i][j][reg] + bkv[col0 + j * 16 + l15]);
        const int r = rblk * 128 + wr * 64 + lane;
        const int b = r >> 11, n = r & (SEQ - 1);
        const size_t vtbase = (((size_t)b * NHEADS + h) * 64) * SEQ;
#pragma unroll
        for (int e8 = 0; e8 < 8; e8++) {
            short8 v = *(const short8*)&Ts[wave][lane][e8 * 8];
#pragma unroll
            for (int e = 0; e < 8; e++)
                VT[vtbase + (size_t)(e8 * 8 + e) * SEQ + n] = v[e];
        }
    }
}

// Band store with COMPILE-TIME jd index: keeps o[][] in registers (dynamic
// indexing demotes the whole array to scratch).
template <int JD, bool FIRST>
__device__ __forceinline__ void band_store(float* __restrict__ Ot,
                                           const f32x4 (&o)[4][4],
                                           int l15, int q) {
#pragma unroll
    for (int qc = 0; qc < 4; qc++)
#pragma unroll
        for (int reg = 0; reg < 4; reg++) {
            float* dst = &Ot[(qc * 16 + l15) * 68 + JD * 16 + q * 4 + reg];
            if (FIRST) *dst = o[JD][qc][reg];
            else       *dst += o[JD][qc][reg];
        }
}

// One rotated pipeline body (tile t) — r7/r9 v9b verbatim EXCEPT the pure
// 20-MFMA PV cluster is wrapped in s_setprio (T5, isolated this round):
// waves in this barrier-free loop drift out of phase, so the CU scheduler
// can prefer the wave in its matrix phase over siblings issuing loads/exp2
// (m191: +4-7% attn; the r1 bundle never isolated it).
// INVARIANTS on entry: kfCur=K(t), vfPN=V(t-1), PdR=P(t-1).
__device__ __forceinline__ void attn_body(
    int t, bool doLoad,
    const short* __restrict__ kbase, const short* __restrict__ vbase,
    const short8 (&qf)[4][2], const short8& ones,
    short8 (&kfCur)[2][2], short8 (&kfNxt)[2][2], short8 (&vfPN)[4],
    unsigned int* __restrict__ PdW, unsigned int* __restrict__ PdR,
    int l15, int q, f32x4 (&o)[4][4], f32x4 (&osum)[4])
{
    short8 pf[4];
#pragma unroll
    for (int qc = 0; qc < 4; qc++) {
        u32x4 pr = *(const u32x4*)&PdR[(qc * 16 + l15) * 20 + 4 * q];
        pf[qc] = __builtin_bit_cast(short8, pr);
    }

#pragma unroll
    for (int kt = 0; kt < 2; kt++)
#pragma unroll
        for (int qc = 0; qc < 4; qc++) {
            f32x4 z = f32x4{0.f, 0.f, 0.f, 0.f};
            z = __builtin_amdgcn_mfma_f32_16x16x32_bf16(kfCur[kt][0], qf[qc][0], z, 0, 0, 0);
            z = __builtin_amdgcn_mfma_f32_16x16x32_bf16(kfCur[kt][1], qf[qc][1], z, 0, 0, 0);
            u32x2 d2;
            d2[0] = pack_bf2(__builtin_amdgcn_exp2f(z[0]), __builtin_amdgcn_exp2f(z[1]));
            d2[1] = pack_bf2(__builtin_amdgcn_exp2f(z[2]), __builtin_amdgcn_exp2f(z[3]));
            *(u32x2*)&PdW[(qc * 16 + l15) * 20 + kt * 8 + 2 * q] = d2;
        }

    if (doLoad) {
#pragma unroll
        for (int kt = 0; kt < 2; kt++)
#pragma unroll
            for (int dh = 0; dh < 2; dh++)
                kfNxt[kt][dh] = *(const short8*)(kbase +
                    (size_t)((t + 1) * 128 + kt * 16) * 64 + dh * 32);
    }

    // Pure-MFMA cluster (20 MFMAs): raise wave priority (T5).
    __builtin_amdgcn_s_setprio(1);
#pragma unroll
    for (int qc = 0; qc < 4; qc++)
        osum[qc] = __builtin_amdgcn_mfma_f32_16x16x32_bf16(ones, pf[qc], osum[qc], 0, 0, 0);
#pragma unroll
    for (int jd = 0; jd < 4; jd++)
#pragma unroll
        for (int qc = 0; qc < 4; qc++)
            o[jd][qc] = __builtin_amdgcn_mfma_f32_16x16x32_bf16(vfPN[jd], pf[qc], o[jd][qc], 0, 0, 0);
    __builtin_amdgcn_s_setprio(0);

    if (doLoad) {
#pragma unroll
        for (int jd = 0; jd < 4; jd++)
            vfPN[jd] = *(const short8*)(vbase + (size_t)(jd * 16) * SEQ + (t + 1) * 128);
    }
}

// ---------------------------------------------------------------------------
// Flash attention — r9 v9b (best measured: 140.4-141.4us, total 330.7) with
// ONE isolated change: setprio around the PV cluster (T5). r10's VALU
// denominator reverted (VALUBusy +9pts, +1.5us). 2 blocks/CU fat waves
// (r8: occupancy 3/CU was -11%). bh-chunked XCD swizzle (FETCH -63%).
// ---------------------------------------------------------------------------
__global__ __launch_bounds__(256, 2) void attn_fa(
    const short* __restrict__ Q,   // [B][H][N][64] bf16, pre-scaled QSCALE
    const short* __restrict__ Kk,  // [B][H][N][64] bf16
    const short* __restrict__ VT,  // [B][H][64][N] bf16
    float* __restrict__ Out)       // [B][N][1024] fp32
{
    __shared__ __align__(16) char smem_raw[40960];

    const int tid = threadIdx.x;
    const int w = tid >> 6, lane = tid & 63;
    const int q = lane >> 4, l15 = lane & 15;
    // bh-chunked XCD swizzle: XCD k gets bh in [8k,8k+8), qt fastest.
    const int lin = blockIdx.y * 64 + blockIdx.x;
    const int swz = (lin & 7) * 256 + (lin >> 3);
    const int bh = swz >> 5;
    const int qt = swz & 31;
    const int b = bh >> 4, h = bh & 15;
    const size_t hb = (size_t)bh * SEQ * 64;
    const size_t vb = (size_t)bh * 64 * SEQ;

    unsigned int* PdA = (unsigned int*)smem_raw + w * 2560;  // even-t buffer
    unsigned int* PdB = PdA + 1280;                          // odd-t buffer
    float* Ot = (float*)smem_raw;                            // [64][68]
    float* Lred = (float*)smem_raw + 64 * 68;                // [4][64]

    short8 qf[4][2];
#pragma unroll
    for (int qc = 0; qc < 4; qc++)
#pragma unroll
        for (int dh = 0; dh < 2; dh++)
            qf[qc][dh] = *(const short8*)(Q + hb +
                (size_t)(qt * 64 + qc * 16 + l15) * 64 + dh * 32 + q * 8);

    short8 ones;
#pragma unroll
    for (int e = 0; e < 8; e++) ones[e] = (short)0x3F80;

    f32x4 o[4][4];
#pragma unroll
    for (int jd = 0; jd < 4; jd++)
#pragma unroll
        for (int qc = 0; qc < 4; qc++) o[jd][qc] = f32x4{0.f, 0.f, 0.f, 0.f};
    f32x4 osum[4];
#pragma unroll
    for (int qc = 0; qc < 4; qc++) osum[qc] = f32x4{0.f, 0.f, 0.f, 0.f};

    const short* kbase = Kk + hb + (size_t)(w * 32 + l15) * 64 + q * 8;
    const short* vbase = VT + vb + (size_t)l15 * SEQ + w * 32 + q * 8;

    short8 kfA[2][2], kfB[2][2], vfA[4], vfB[4];

    // ---- prologue: load K/V(0), QK(0)->PdA, load K(1) AND V(1) ----
#pragma unroll
    for (int kt = 0; kt < 2; kt++)
#pragma unroll
        for (int dh = 0; dh < 2; dh++)
            kfA[kt][dh] = *(const short8*)(kbase + (size_t)(kt * 16) * 64 + dh * 32);
#pragma unroll
    for (int jd = 0; jd < 4; jd++)
        vfA[jd] = *(const short8*)(vbase + (size_t)(jd * 16) * SEQ);
#pragma unroll
    for (int kt = 0; kt < 2; kt++)
#pragma unroll
        for (int qc = 0; qc < 4; qc++) {
            f32x4 z = f32x4{0.f, 0.f, 0.f, 0.f};
            z = __builtin_amdgcn_mfma_f32_16x16x32_bf16(kfA[kt][0], qf[qc][0], z, 0, 0, 0);
            z = __builtin_amdgcn_mfma_f32_16x16x32_bf16(kfA[kt][1], qf[qc][1], z, 0, 0, 0);
            u32x2 d2;
            d2[0] = pack_bf2(__builtin_amdgcn_exp2f(z[0]), __builtin_amdgcn_exp2f(z[1]));
            d2[1] = pack_bf2(__builtin_amdgcn_exp2f(z[2]), __builtin_amdgcn_exp2f(z[3]));
            *(u32x2*)&PdA[(qc * 16 + l15) * 20 + kt * 8 + 2 * q] = d2;
        }
#pragma unroll
    for (int kt = 0; kt < 2; kt++)
#pragma unroll
        for (int dh = 0; dh < 2; dh++)
            kfB[kt][dh] = *(const short8*)(kbase + (size_t)(128 + kt * 16) * 64 + dh * 32);
#pragma unroll
    for (int jd = 0; jd < 4; jd++)
        vfB[jd] = *(const short8*)(vbase + (size_t)(jd * 16) * SEQ + 128);

    for (int t = 1; t < 15; t += 2) {
        attn_body(t,     true, kbase, vbase, qf, ones, kfB, kfA, vfA, PdB, PdA, l15, q, o, osum);
        attn_body(t + 1, true, kbase, vbase, qf, ones, kfA, kfB, vfB, PdA, PdB, l15, q, o, osum);
    }
    attn_body(15, false, kbase, vbase, qf, ones, kfB, kfA, vfA, PdB, PdA, l15, q, o, osum);

    // ---- drain: PV(15) from PdB with vfB (= V(15), loaded by body(14)) ----
    {
        short8 pf[4];
#pragma unroll
        for (int qc = 0; qc < 4; qc++) {
            u32x4 pr = *(const u32x4*)&PdB[(qc * 16 + l15) * 20 + 4 * q];
            pf[qc] = __builtin_bit_cast(short8, pr);
        }
        __builtin_amdgcn_s_setprio(1);
#pragma unroll
        for (int qc = 0; qc < 4; qc++)
            osum[qc] = __builtin_amdgcn_mfma_f32_16x16x32_bf16(ones, pf[qc], osum[qc], 0, 0, 0);
#pragma unroll
        for (int jd = 0; jd < 4; jd++)
#pragma unroll
            for (int qc = 0; qc < 4; qc++)
                o[jd][qc] = __builtin_amdgcn_mfma_f32_16x16x32_bf16(vfB[jd], pf[qc], o[jd][qc], 0, 0, 0);
        __builtin_amdgcn_s_setprio(0);
    }

    // ---- epilogue: phase-accumulate O^T into Ot (aliases Pd), then store ----
    __syncthreads();  // Pd dead everywhere
#pragma unroll
    for (int p = 0; p < 4; p++) {
        const int jd = (w + p) & 3;
        if (p == 0) {
            switch (jd) {
            case 0: band_store<0, true>(Ot, o, l15, q); break;
            case 1: band_store<1, true>(Ot, o, l15, q); break;
            case 2: band_store<2, true>(Ot, o, l15, q); break;
            case 3: band_store<3, true>(Ot, o, l15, q); break;
            }
            if (q == 0) {
#pragma unroll
                for (int qc = 0; qc < 4; qc++)
                    Lred[w * 64 + qc * 16 + l15] = osum[qc][0];
            }
        } else {
            switch (jd) {
            case 0: band_store<0, false>(Ot, o, l15, q); break;
            case 1: band_store<1, false>(Ot, o, l15, q); break;
            case 2: band_store<2, false>(Ot, o, l15, q); break;
            case 3: band_store<3, false>(Ot, o, l15, q); break;
            }
        }
        __syncthreads();
    }

    // coalesced store: 4 lanes cover one row's 16 floats each -> 64 B lines
    const int row = tid >> 2, c = tid & 3;
    float l = Lred[row] + Lred[64 + row] + Lred[128 + row] + Lred[192 + row];
    float inv = 1.f / l;
    float* obase = Out + ((size_t)b * SEQ + qt * 64 + row) * CDIM + h * 64;
#pragma unroll
    for (int i = 0; i < 4; i++) {
        f32x4 t = *(const f32x4*)&Ot[row * 68 + (c + 4 * i) * 4];
        *(f32x4*)(obase + (c + 4 * i) * 4) = t * inv;
    }
}

extern "C" void kernel_launch(void* const* d_in, const int* in_sizes, int n_in,
                              void* d_out, int out_size, void* d_ws, size_t ws_size,
                              hipStream_t stream) {
    const float* x1 = (const float*)d_in[0];
    const float* x2 = (const float*)d_in[1];
    const float* wq = (const float*)d_in[2];
    const float* bq = (const float*)d_in[3];
    const float* wkv = (const float*)d_in[4];
    const float* bkv = (const float*)d_in[5];
    const float* gq = (const float*)d_in[6];
    const float* btq = (const float*)d_in[7];
    const float* gk = (const float*)d_in[8];
    const float* btk = (const float*)d_in[9];
    float* out = (float*)d_out;

    short* a1 = (short*)d_ws;                          // [8192][1024] bf16
    short* a2 = a1 + (size_t)ROWS * CDIM;
    short* wqT = a2 + (size_t)ROWS * CDIM;             // [1024][1024]
    short* wkvT = wqT + (size_t)CDIM * CDIM;           // [2048][1024]
    short* qln = wkvT + (size_t)2 * CDIM * CDIM;       // [B][H][N][64]
    short* kln = qln + (size_t)ROWS * CDIM;            // [B][H][N][64]
    short* vt = kln + (size_t)ROWS * CDIM;             // [B][H][64][N]

    const int n8 = ROWS * CDIM / 8;
    cvt2_bf16<<<dim3(2 * n8 / 256), 256, 0, stream>>>(x1, x2, a1, a2, n8);
    wtrans2<<<dim3(48, 16), 256, 0, stream>>>(wq, wqT, wkv, wkvT);
    gemm_all<<<dim3(1536), 256, 0, stream>>>(a1, a2, wqT, wkvT, bq, bkv,
                                             gq, btq, gk, btk, qln, kln, vt);
    attn_fa<<<dim3(64, 32), 256, 0, stream>>>(qln, kln, vt, out);
}

// Round 12
// 324.409 us; speedup vs baseline: 1.0303x; 1.0186x over previous
//
#include <hip/hip_runtime.h>
#include <hip/hip_bf16.h>

#define NHEADS 16
#define HDIM 64
#define BATCH 4
#define SEQ 2048
#define CDIM 1024
#define ROWS (BATCH * SEQ)  // 8192
// attention scale 1/sqrt(64) folded with log2(e) so attn uses exp2
#define QSCALE (0.125f * 1.44269504088896f)

typedef __attribute__((ext_vector_type(8))) short short8;
typedef __attribute__((ext_vector_type(4))) float f32x4;
typedef __attribute__((ext_vector_type(4))) unsigned int u32x4;
typedef __attribute__((ext_vector_type(2))) unsigned int u32x2;

__device__ inline short f2bf(float f) {
    unsigned int u = __builtin_bit_cast(unsigned int, f);
    unsigned int r = (u + 0x7fffu + ((u >> 16) & 1u)) >> 16;
    return (short)r;
}

__device__ __forceinline__ void gll16(const void* g, void* l) {
    __builtin_amdgcn_global_load_lds(
        (const __attribute__((address_space(1))) unsigned int*)g,
        (__attribute__((address_space(3))) unsigned int*)l, 16, 0, 0);
}

// pack two f32 to bf16x2 (truncate): low = hi16(a), high = hi16(b).
// truncation bias cancels between PV numerator and ones-MFMA denominator.
__device__ __forceinline__ unsigned int pack_bf2(float a, float b) {
    return __builtin_amdgcn_perm(__builtin_bit_cast(unsigned int, b),
                                 __builtin_bit_cast(unsigned int, a), 0x07060302u);
}

// ---------------------------------------------------------------------------
// Pre-pass 1 (fused): fp32 -> bf16 for x1 AND x2 in one dispatch.
// ---------------------------------------------------------------------------
__global__ __launch_bounds__(256) void cvt2_bf16(const float* __restrict__ s1,
                                                 const float* __restrict__ s2,
                                                 short* __restrict__ d1,
                                                 short* __restrict__ d2, int n8each) {
    int i = blockIdx.x * 256 + threadIdx.x;
    const float* src = s1;
    short* dst = d1;
    if (i >= n8each) { i -= n8each; src = s2; dst = d2; }
    f32x4 a = ((const f32x4*)src)[i * 2];
    f32x4 b = ((const f32x4*)src)[i * 2 + 1];
    short8 o;
    o[0] = f2bf(a[0]); o[1] = f2bf(a[1]); o[2] = f2bf(a[2]); o[3] = f2bf(a[3]);
    o[4] = f2bf(b[0]); o[5] = f2bf(b[1]); o[6] = f2bf(b[2]); o[7] = f2bf(b[3]);
    ((short8*)dst)[i] = o;
}

// ---------------------------------------------------------------------------
// Pre-pass 2 (fused): W [K=1024][Nw] fp32 -> W^T [Nw][1024] bf16, wq AND wkv.
// blockIdx.x < 16 -> wq (Nw=1024); else wkv (Nw=2048).
// ---------------------------------------------------------------------------
__global__ __launch_bounds__(256) void wtrans2(const float* __restrict__ Wq,
                                               short* __restrict__ WQT,
                                               const float* __restrict__ Wkv,
                                               short* __restrict__ WKVT) {
    __shared__ short T[64][72];
    const int t = threadIdx.x;
    const int bx = blockIdx.x;
    const float* W;
    short* WT;
    int Nw, n0;
    if (bx < 16) { W = Wq;  WT = WQT;  Nw = 1024; n0 = bx * 64; }
    else         { W = Wkv; WT = WKVT; Nw = 2048; n0 = (bx - 16) * 64; }
    const int k0 = blockIdx.y * 64;
    const int kl = t >> 2, c4 = (t & 3) * 16;
    const float* src = W + (size_t)(k0 + kl) * Nw + n0 + c4;
    short8 s0, s1;
#pragma unroll
    for (int e = 0; e < 2; e++) {
        f32x4 u = *(const f32x4*)(src + e * 4);
        s0[e * 4 + 0] = f2bf(u[0]); s0[e * 4 + 1] = f2bf(u[1]);
        s0[e * 4 + 2] = f2bf(u[2]); s0[e * 4 + 3] = f2bf(u[3]);
        f32x4 v = *(const f32x4*)(src + 8 + e * 4);
        s1[e * 4 + 0] = f2bf(v[0]); s1[e * 4 + 1] = f2bf(v[1]);
        s1[e * 4 + 2] = f2bf(v[2]); s1[e * 4 + 3] = f2bf(v[3]);
    }
    *(short8*)&T[kl][c4] = s0;
    *(short8*)&T[kl][c4 + 8] = s1;
    __syncthreads();
#pragma unroll
    for (int pass = 0; pass < 2; pass++) {
        int n = (t >> 3) + pass * 32;
        short8 o;
#pragma unroll
        for (int e = 0; e < 8; e++) o[e] = T[(t & 7) * 8 + e][n];
        *(short8*)(WT + (size_t)(n0 + n) * 1024 + k0 + (t & 7) * 8) = o;
    }
}

// ---------------------------------------------------------------------------
// Fused GEMM, r12: minimum-2-PHASE double-buffered K-loop (T3 recipe).
// Old structure (m97-style) had TWO barriers per BK=32 step and a serial
// stage->vmcnt(0)-drain->compute chain; at this small-K shape (32 steps)
// that stall never amortizes (m102 shape curve, m233: stall ~72%). New:
// issue next tile's global_load_lds into the OTHER buffer BEFORE computing
// the current one; ONE __syncthreads per step (its vmcnt0 drains the stage
// that had the whole MFMA phase to fly). LDS: As/Bs x2 = 32768 B; V-path
// Ts alias 34816 B -> footprint unchanged.
// Range-partitioned swizzle kept (r9): lin<512 Q-part, else KV-part;
// 512%8==0 keeps per-part XCD assignment = split dispatches.
// ---------------------------------------------------------------------------
__global__ __launch_bounds__(256) void gemm_all(
    const short* __restrict__ A1,    // [8192][1024] bf16 (x1)
    const short* __restrict__ A2,    // [8192][1024] bf16 (x2)
    const short* __restrict__ WQT,   // [1024][1024] bf16
    const short* __restrict__ WKVT,  // [2048][1024] bf16
    const float* __restrict__ bq,    // [1024]
    const float* __restrict__ bkv,   // [2048]
    const float* __restrict__ gq, const float* __restrict__ btq,
    const float* __restrict__ gk, const float* __restrict__ btk,
    short* __restrict__ QOut,        // [B][H][N][64] bf16 (pre-scaled QSCALE)
    short* __restrict__ KOut,        // [B][H][N][64] bf16
    short* __restrict__ VT)          // [B][H][64][N] bf16
{
    __shared__ __align__(16) char smem[34816];
    short (*As0)[32] = (short (*)[32])smem;            // ph0 A [128][32]
    short (*As1)[32] = (short (*)[32])(smem + 8192);   // ph1 A
    short (*Bs0)[32] = (short (*)[32])(smem + 16384);  // ph0 B
    short (*Bs1)[32] = (short (*)[32])(smem + 24576);  // ph1 B

    const int tid = threadIdx.x;
    const int wave = tid >> 6, lane = tid & 63;
    const int wr = wave >> 1, wc = wave & 1;
    const int quad = lane >> 4, l15 = lane & 15;

    const int lin = blockIdx.x;                      // grid (1536)
    const bool isQ = lin < 512;
    int rblk, cblk;
    if (isQ) {
        const int swz = (lin & 7) * 64 + (lin >> 3);       // r1 Q swizzle
        rblk = swz >> 3; cblk = swz & 7;
    } else {
        const int kl = lin - 512;                          // kl%8 == lin%8
        const int swz = (kl & 7) * 128 + (kl >> 3);        // r1 KV swizzle
        rblk = swz >> 4; cblk = swz & 15;
    }
    const short* Ap = isQ ? A1 : A2;
    const short* BT = isQ ? WQT : WKVT;

    f32x4 acc[4][4];
#pragma unroll
    for (int i = 0; i < 4; i++)
#pragma unroll
        for (int j = 0; j < 4; j++) acc[i][j] = f32x4{0.f, 0.f, 0.f, 0.f};

    const int srow = wave * 32 + (lane >> 2);
    const int scol = (lane & 3) * 8;

    // stage one BK=32 tile of A and B into the given buffers
    auto stage = [&](short (*Ad)[32], short (*Bd)[32], int k0) {
#pragma unroll
        for (int c = 0; c < 2; c++) {
            gll16(Ap + (size_t)(rblk * 128 + srow + c * 16) * CDIM + k0 + scol,
                  &Ad[srow + c * 16][scol]);
            gll16(BT + (size_t)(cblk * 128 + srow + c * 16) * CDIM + k0 + scol,
                  &Bd[srow + c * 16][scol]);
        }
    };
    // 16 MFMAs on one staged tile
    auto compute = [&](short (*Ad)[32], short (*Bd)[32]) {
        short8 af[4], bfr[4];
#pragma unroll
        for (int i = 0; i < 4; i++)
            af[i] = *(const short8*)&Ad[wr * 64 + i * 16 + l15][quad * 8];
#pragma unroll
        for (int j = 0; j < 4; j++)
            bfr[j] = *(const short8*)&Bd[wc * 64 + j * 16 + l15][quad * 8];
#pragma unroll
        for (int i = 0; i < 4; i++)
#pragma unroll
            for (int j = 0; j < 4; j++)
                acc[i][j] = __builtin_amdgcn_mfma_f32_16x16x32_bf16(af[i], bfr[j], acc[i][j], 0, 0, 0);
    };

    // prologue: stage tile 0, drain (syncthreads = vmcnt0+lgkm0+barrier)
    stage(As0, Bs0, 0);
    __syncthreads();
    // steady state: stage(next, other buffer) BEFORE compute(current);
    // one barrier per step. Pairwise unrolled with named buffers.
    for (int k0 = 0; k0 < CDIM; k0 += 64) {
        stage(As1, Bs1, k0 + 32);            // k0+32 <= 992 < CDIM always
        compute(As0, Bs0);
        __syncthreads();                     // As1/Bs1 ready; As0/Bs0 reads done
        if (k0 + 64 < CDIM) stage(As0, Bs0, k0 + 64);
        compute(As1, Bs1);
        __syncthreads();                     // As0/Bs0 ready; As1/Bs1 reads done
    }

    const int col0 = cblk * 128 + wc * 64;
    const int g = col0 >> 6;   // Q: [0,16); KV: [0,32)

    if (isQ || g < NHEADS) {  // ---- Q or K: bias + per-head LayerNorm ----
        const float* bias  = isQ ? bq : bkv;
        const float* gamma = isQ ? gq : gk;
        const float* beta  = isQ ? btq : btk;
        short* Out = isQ ? QOut : KOut;
        const float scale = isQ ? QSCALE : 1.f;
        const int h = g;
        float bv[4], gv[4], btv[4];
#pragma unroll
        for (int j = 0; j < 4; j++) {
            int d = j * 16 + l15;
            bv[j] = bias[col0 + d];
            gv[j] = gamma[d];
            btv[j] = beta[d];
        }
#pragma unroll
        for (int i = 0; i < 4; i++) {
            int rowl = rblk * 128 + wr * 64 + i * 16 + quad * 4;
#pragma unroll
            for (int reg = 0; reg < 4; reg++) {
                float x[4], s = 0.f, s2 = 0.f;
#pragma unroll
                for (int j = 0; j < 4; j++) {
                    x[j] = acc[i][j][reg] + bv[j];
                    s += x[j];
                    s2 += x[j] * x[j];
                }
#pragma unroll
                for (int m = 1; m < 16; m <<= 1) {
                    s += __shfl_xor(s, m);
                    s2 += __shfl_xor(s2, m);
                }
                float mean = s * (1.f / 64.f);
                float var = s2 * (1.f / 64.f) - mean * mean;
                float rstd = rsqrtf(var + 1e-5f);
                int r = rowl + reg;
                int b = r >> 11, n = r & (SEQ - 1);
                size_t base = (((size_t)b * NHEADS + h) * SEQ + n) * 64;
#pragma unroll
                for (int j = 0; j < 4; j++) {
                    float y = ((x[j] - mean) * rstd * gv[j] + btv[j]) * scale;
                    Out[base + j * 16 + l15] = f2bf(y);
                }
            }
        }
    } else {  // ---- V: bias -> wave-local transpose (Ts aliases As/Bs) ----
        const int h = g - NHEADS;
        __syncthreads();  // all staging buffers dead before Ts alias
        short (*Ts)[64][68] = (short (*)[64][68])smem;  // [4][64][68]
#pragma unroll
        for (int i = 0; i < 4; i++)
#pragma unroll
            for (int reg = 0; reg < 4; reg++)
#pragma unroll
                for (int j = 0; j < 4; j++)
                    Ts[wave][i * 16 + quad * 4 + reg][j * 16 + l15] =
                        f2bf(acc[i][j][reg] + bkv[col0 + j * 16 + l15]);
        const int r = rblk * 128 + wr * 64 + lane;
        const int b = r >> 11, n = r & (SEQ - 1);
        const size_t vtbase = (((size_t)b * NHEADS + h) * 64) * SEQ;
#pragma unroll
        for (int e8 = 0; e8 < 8; e8++) {
            short8 v = *(const short8*)&Ts[wave][lane][e8 * 8];
#pragma unroll
            for (int e = 0; e < 8; e++)
                VT[vtbase + (size_t)(e8 * 8 + e) * SEQ + n] = v[e];
        }
    }
}

// Band store with COMPILE-TIME jd index: keeps o[][] in registers (dynamic
// indexing demotes the whole array to scratch).
template <int JD, bool FIRST>
__device__ __forceinline__ void band_store(float* __restrict__ Ot,
                                           const f32x4 (&o)[4][4],
                                           int l15, int q) {
#pragma unroll
    for (int qc = 0; qc < 4; qc++)
#pragma unroll
        for (int reg = 0; reg < 4; reg++) {
            float* dst = &Ot[(qc * 16 + l15) * 68 + JD * 16 + q * 4 + reg];
            if (FIRST) *dst = o[JD][qc][reg];
            else       *dst += o[JD][qc][reg];
        }
}

// One rotated pipeline body (tile t) — r11 verbatim (setprio kept: neutral
// but not harmful). INVARIANTS on entry: kfCur=K(t), vfPN=V(t-1), PdR=P(t-1).
__device__ __forceinline__ void attn_body(
    int t, bool doLoad,
    const short* __restrict__ kbase, const short* __restrict__ vbase,
    const short8 (&qf)[4][2], const short8& ones,
    short8 (&kfCur)[2][2], short8 (&kfNxt)[2][2], short8 (&vfPN)[4],
    unsigned int* __restrict__ PdW, unsigned int* __restrict__ PdR,
    int l15, int q, f32x4 (&o)[4][4], f32x4 (&osum)[4])
{
    short8 pf[4];
#pragma unroll
    for (int qc = 0; qc < 4; qc++) {
        u32x4 pr = *(const u32x4*)&PdR[(qc * 16 + l15) * 20 + 4 * q];
        pf[qc] = __builtin_bit_cast(short8, pr);
    }

#pragma unroll
    for (int kt = 0; kt < 2; kt++)
#pragma unroll
        for (int qc = 0; qc < 4; qc++) {
            f32x4 z = f32x4{0.f, 0.f, 0.f, 0.f};
            z = __builtin_amdgcn_mfma_f32_16x16x32_bf16(kfCur[kt][0], qf[qc][0], z, 0, 0, 0);
            z = __builtin_amdgcn_mfma_f32_16x16x32_bf16(kfCur[kt][1], qf[qc][1], z, 0, 0, 0);
            u32x2 d2;
            d2[0] = pack_bf2(__builtin_amdgcn_exp2f(z[0]), __builtin_amdgcn_exp2f(z[1]));
            d2[1] = pack_bf2(__builtin_amdgcn_exp2f(z[2]), __builtin_amdgcn_exp2f(z[3]));
            *(u32x2*)&PdW[(qc * 16 + l15) * 20 + kt * 8 + 2 * q] = d2;
        }

    if (doLoad) {
#pragma unroll
        for (int kt = 0; kt < 2; kt++)
#pragma unroll
            for (int dh = 0; dh < 2; dh++)
                kfNxt[kt][dh] = *(const short8*)(kbase +
                    (size_t)((t + 1) * 128 + kt * 16) * 64 + dh * 32);
    }

    // Pure-MFMA cluster (20 MFMAs): raise wave priority (T5).
    __builtin_amdgcn_s_setprio(1);
#pragma unroll
    for (int qc = 0; qc < 4; qc++)
        osum[qc] = __builtin_amdgcn_mfma_f32_16x16x32_bf16(ones, pf[qc], osum[qc], 0, 0, 0);
#pragma unroll
    for (int jd = 0; jd < 4; jd++)
#pragma unroll
        for (int qc = 0; qc < 4; qc++)
            o[jd][qc] = __builtin_amdgcn_mfma_f32_16x16x32_bf16(vfPN[jd], pf[qc], o[jd][qc], 0, 0, 0);
    __builtin_amdgcn_s_setprio(0);

    if (doLoad) {
#pragma unroll
        for (int jd = 0; jd < 4; jd++)
            vfPN[jd] = *(const short8*)(vbase + (size_t)(jd * 16) * SEQ + (t + 1) * 128);
    }
}

// ---------------------------------------------------------------------------
// Flash attention — r11 verbatim (140.4us; template swept: prefetch/thin-
// waves/occupancy/pipeline/VALU-denominator/setprio all null or negative;
// pinned at ~550 TF latency-structured). 2 blocks/CU fat waves; bh-chunked
// XCD swizzle (FETCH -63%).
// ---------------------------------------------------------------------------
__global__ __launch_bounds__(256, 2) void attn_fa(
    const short* __restrict__ Q,   // [B][H][N][64] bf16, pre-scaled QSCALE
    const short* __restrict__ Kk,  // [B][H][N][64] bf16
    const short* __restrict__ VT,  // [B][H][64][N] bf16
    float* __restrict__ Out)       // [B][N][1024] fp32
{
    __shared__ __align__(16) char smem_raw[40960];

    const int tid = threadIdx.x;
    const int w = tid >> 6, lane = tid & 63;
    const int q = lane >> 4, l15 = lane & 15;
    // bh-chunked XCD swizzle: XCD k gets bh in [8k,8k+8), qt fastest.
    const int lin = blockIdx.y * 64 + blockIdx.x;
    const int swz = (lin & 7) * 256 + (lin >> 3);
    const int bh = swz >> 5;
    const int qt = swz & 31;
    const int b = bh >> 4, h = bh & 15;
    const size_t hb = (size_t)bh * SEQ * 64;
    const size_t vb = (size_t)bh * 64 * SEQ;

    unsigned int* PdA = (unsigned int*)smem_raw + w * 2560;  // even-t buffer
    unsigned int* PdB = PdA + 1280;                          // odd-t buffer
    float* Ot = (float*)smem_raw;                            // [64][68]
    float* Lred = (float*)smem_raw + 64 * 68;                // [4][64]

    short8 qf[4][2];
#pragma unroll
    for (int qc = 0; qc < 4; qc++)
#pragma unroll
        for (int dh = 0; dh < 2; dh++)
            qf[qc][dh] = *(const short8*)(Q + hb +
                (size_t)(qt * 64 + qc * 16 + l15) * 64 + dh * 32 + q * 8);

    short8 ones;
#pragma unroll
    for (int e = 0; e < 8; e++) ones[e] = (short)0x3F80;

    f32x4 o[4][4];
#pragma unroll
    for (int jd = 0; jd < 4; jd++)
#pragma unroll
        for (int qc = 0; qc < 4; qc++) o[jd][qc] = f32x4{0.f, 0.f, 0.f, 0.f};
    f32x4 osum[4];
#pragma unroll
    for (int qc = 0; qc < 4; qc++) osum[qc] = f32x4{0.f, 0.f, 0.f, 0.f};

    const short* kbase = Kk + hb + (size_t)(w * 32 + l15) * 64 + q * 8;
    const short* vbase = VT + vb + (size_t)l15 * SEQ + w * 32 + q * 8;

    short8 kfA[2][2], kfB[2][2], vfA[4], vfB[4];

    // ---- prologue: load K/V(0), QK(0)->PdA, load K(1) AND V(1) ----
#pragma unroll
    for (int kt = 0; kt < 2; kt++)
#pragma unroll
        for (int dh = 0; dh < 2; dh++)
            kfA[kt][dh] = *(const short8*)(kbase + (size_t)(kt * 16) * 64 + dh * 32);
#pragma unroll
    for (int jd = 0; jd < 4; jd++)
        vfA[jd] = *(const short8*)(vbase + (size_t)(jd * 16) * SEQ);
#pragma unroll
    for (int kt = 0; kt < 2; kt++)
#pragma unroll
        for (int qc = 0; qc < 4; qc++) {
            f32x4 z = f32x4{0.f, 0.f, 0.f, 0.f};
            z = __builtin_amdgcn_mfma_f32_16x16x32_bf16(kfA[kt][0], qf[qc][0], z, 0, 0, 0);
            z = __builtin_amdgcn_mfma_f32_16x16x32_bf16(kfA[kt][1], qf[qc][1], z, 0, 0, 0);
            u32x2 d2;
            d2[0] = pack_bf2(__builtin_amdgcn_exp2f(z[0]), __builtin_amdgcn_exp2f(z[1]));
            d2[1] = pack_bf2(__builtin_amdgcn_exp2f(z[2]), __builtin_amdgcn_exp2f(z[3]));
            *(u32x2*)&PdA[(qc * 16 + l15) * 20 + kt * 8 + 2 * q] = d2;
        }
#pragma unroll
    for (int kt = 0; kt < 2; kt++)
#pragma unroll
        for (int dh = 0; dh < 2; dh++)
            kfB[kt][dh] = *(const short8*)(kbase + (size_t)(128 + kt * 16) * 64 + dh * 32);
#pragma unroll
    for (int jd = 0; jd < 4; jd++)
        vfB[jd] = *(const short8*)(vbase + (size_t)(jd * 16) * SEQ + 128);

    for (int t = 1; t < 15; t += 2) {
        attn_body(t,     true, kbase, vbase, qf, ones, kfB, kfA, vfA, PdB, PdA, l15, q, o, osum);
        attn_body(t + 1, true, kbase, vbase, qf, ones, kfA, kfB, vfB, PdA, PdB, l15, q, o, osum);
    }
    attn_body(15, false, kbase, vbase, qf, ones, kfB, kfA, vfA, PdB, PdA, l15, q, o, osum);

    // ---- drain: PV(15) from PdB with vfB (= V(15), loaded by body(14)) ----
    {
        short8 pf[4];
#pragma unroll
        for (int qc = 0; qc < 4; qc++) {
            u32x4 pr = *(const u32x4*)&PdB[(qc * 16 + l15) * 20 + 4 * q];
            pf[qc] = __builtin_bit_cast(short8, pr);
        }
        __builtin_amdgcn_s_setprio(1);
#pragma unroll
        for (int qc = 0; qc < 4; qc++)
            osum[qc] = __builtin_amdgcn_mfma_f32_16x16x32_bf16(ones, pf[qc], osum[qc], 0, 0, 0);
#pragma unroll
        for (int jd = 0; jd < 4; jd++)
#pragma unroll
            for (int qc = 0; qc < 4; qc++)
                o[jd][qc] = __builtin_amdgcn_mfma_f32_16x16x32_bf16(vfB[jd], pf[qc], o[jd][qc], 0, 0, 0);
        __builtin_amdgcn_s_setprio(0);
    }

    // ---- epilogue: phase-accumulate O^T into Ot (aliases Pd), then store ----
    __syncthreads();  // Pd dead everywhere
#pragma unroll
    for (int p = 0; p < 4; p++) {
        const int jd = (w + p) & 3;
        if (p == 0) {
            switch (jd) {
            case 0: band_store<0, true>(Ot, o, l15, q); break;
            case 1: band_store<1, true>(Ot, o, l15, q); break;
            case 2: band_store<2, true>(Ot, o, l15, q); break;
            case 3: band_store<3, true>(Ot, o, l15, q); break;
            }
            if (q == 0) {
#pragma unroll
                for (int qc = 0; qc < 4; qc++)
                    Lred[w * 64 + qc * 16 + l15] = osum[qc][0];
            }
        } else {
            switch (jd) {
            case 0: band_store<0, false>(Ot, o, l15, q); break;
            case 1: band_store<1, false>(Ot, o, l15, q); break;
            case 2: band_store<2, false>(Ot, o, l15, q); break;
            case 3: band_store<3, false>(Ot, o, l15, q); break;
            }
        }
        __syncthreads();
    }

    // coalesced store: 4 lanes cover one row's 16 floats each -> 64 B lines
    const int row = tid >> 2, c = tid & 3;
    float l = Lred[row] + Lred[64 + row] + Lred[128 + row] + Lred[192 + row];
    float inv = 1.f / l;
    float* obase = Out + ((size_t)b * SEQ + qt * 64 + row) * CDIM + h * 64;
#pragma unroll
    for (int i = 0; i < 4; i++) {
        f32x4 t = *(const f32x4*)&Ot[row * 68 + (c + 4 * i) * 4];
        *(f32x4*)(obase + (c + 4 * i) * 4) = t * inv;
    }
}

extern "C" void kernel_launch(void* const* d_in, const int* in_sizes, int n_in,
                              void* d_out, int out_size, void* d_ws, size_t ws_size,
                              hipStream_t stream) {
    const float* x1 = (const float*)d_in[0];
    const float* x2 = (const float*)d_in[1];
    const float* wq = (const float*)d_in[2];
    const float* bq = (const float*)d_in[3];
    const float* wkv = (const float*)d_in[4];
    const float* bkv = (const float*)d_in[5];
    const float* gq = (const float*)d_in[6];
    const float* btq = (const float*)d_in[7];
    const float* gk = (const float*)d_in[8];
    const float* btk = (const float*)d_in[9];
    float* out = (float*)d_out;

    short* a1 = (short*)d_ws;                          // [8192][1024] bf16
    short* a2 = a1 + (size_t)ROWS * CDIM;
    short* wqT = a2 + (size_t)ROWS * CDIM;             // [1024][1024]
    short* wkvT = wqT + (size_t)CDIM * CDIM;           // [2048][1024]
    short* qln = wkvT + (size_t)2 * CDIM * CDIM;       // [B][H][N][64]
    short* kln = qln + (size_t)ROWS * CDIM;            // [B][H][N][64]
    short* vt = kln + (size_t)ROWS * CDIM;             // [B][H][64][N]

    const int n8 = ROWS * CDIM / 8;
    cvt2_bf16<<<dim3(2 * n8 / 256), 256, 0, stream>>>(x1, x2, a1, a2, n8);
    wtrans2<<<dim3(48, 16), 256, 0, stream>>>(wq, wqT, wkv, wkvT);
    gemm_all<<<dim3(1536), 256, 0, stream>>>(a1, a2, wqT, wkvT, bq, bkv,
                                             gq, btq, gk, btk, qln, kln, vt);
    attn_fa<<<dim3(64, 32), 256, 0, stream>>>(qln, kln, vt, out);
}